// Round 1
// baseline (760.868 us; speedup 1.0000x reference)
//
#include <hip/hip_runtime.h>
#include <hip/hip_bf16.h>
#include <stdint.h>

#define T_TOK 2048
#define H_DIM 1024
#define I_DIM 4096

typedef __attribute__((ext_vector_type(8))) short bf16x8;
typedef __attribute__((ext_vector_type(4))) float f32x4;
typedef unsigned short u16;

__device__ __forceinline__ void gload_lds16(const void* g, void* l) {
  __builtin_amdgcn_global_load_lds((const __attribute__((address_space(1))) void*)g,
                                   (__attribute__((address_space(3))) void*)l, 16, 0, 0);
}

__device__ __forceinline__ u16 f2bf(float f) {
  uint32_t u = __float_as_uint(f);
  u += 0x7fff + ((u >> 16) & 1);   // RNE
  return (u16)(u >> 16);
}

// swizzled LDS read: logical (row, kof elems) from a [*][64]-bf16 tile,
// phys byte = logical byte ^ ((row&7)<<4)
__device__ __forceinline__ bf16x8 lds_read_swz(const u16* base, int row, int kof) {
  int byt = (row * 64 + kof) * 2;
  byt ^= (row & 7) << 4;
  return *(const bf16x8*)((const char*)base + byt);
}

// ---------------- fp32 -> bf16 conversion (vectorized) ----------------
__global__ __launch_bounds__(256) void cvt_kernel(const float* __restrict__ s,
                                                  u16* __restrict__ d, int n) {
  int i = (blockIdx.x * 256 + threadIdx.x) * 8;
  int step = gridDim.x * 256 * 8;
  for (; i < n; i += step) {
    float4 v0 = *(const float4*)(s + i);
    float4 v1 = *(const float4*)(s + i + 4);
    union { u16 h[8]; uint4 q; } o;
    o.h[0] = f2bf(v0.x); o.h[1] = f2bf(v0.y); o.h[2] = f2bf(v0.z); o.h[3] = f2bf(v0.w);
    o.h[4] = f2bf(v1.x); o.h[5] = f2bf(v1.y); o.h[6] = f2bf(v1.z); o.h[7] = f2bf(v1.w);
    *(uint4*)(d + i) = o.q;
  }
}

// ---------------- router: fp32 logits, softmax, top-2 of 9 ----------------
__global__ __launch_bounds__(256) void router_kernel(
    const float* __restrict__ x, const float* __restrict__ rw,
    int* __restrict__ counts, int* __restrict__ lists, float* __restrict__ wlist,
    float* __restrict__ z_sum)
{
  int t = blockIdx.x;
  __shared__ float xs[H_DIM];
  __shared__ float red[9][4];
  const float* xp = x + (size_t)t * H_DIM;
  for (int h = threadIdx.x; h < H_DIM; h += 256) xs[h] = xp[h];
  __syncthreads();
  int lane = threadIdx.x & 63, wid = threadIdx.x >> 6;
  for (int e = 0; e < 9; ++e) {
    float p = 0.f;
    const float* rp = rw + e * H_DIM;
    for (int h = threadIdx.x; h < H_DIM; h += 256) p += xs[h] * rp[h];
#pragma unroll
    for (int off = 32; off > 0; off >>= 1) p += __shfl_down(p, off);
    if (lane == 0) red[e][wid] = p;
  }
  __syncthreads();
  if (threadIdx.x == 0) {
    float lg[9], m = -1e30f;
    for (int e = 0; e < 9; ++e) {
      lg[e] = red[e][0] + red[e][1] + red[e][2] + red[e][3];
      m = fmaxf(m, lg[e]);
    }
    float z = 0.f;
    for (int e = 0; e < 9; ++e) z += lg[e] * lg[e];
    atomicAdd(z_sum, z);
    float p[9], s = 0.f;
    for (int e = 0; e < 9; ++e) { p[e] = expf(lg[e] - m); s += p[e]; }
    // top-2 on logits (same order as probs); ties -> lower index, matching lax.top_k
    int i0 = 0;
    for (int e = 1; e < 9; ++e) if (lg[e] > lg[i0]) i0 = e;
    int i1 = (i0 == 0) ? 1 : 0;
    for (int e = 0; e < 9; ++e) if (e != i0 && lg[e] > lg[i1]) i1 = e;
    float w0 = p[i0] / s, w1 = p[i1] / s;
    float inv = 1.f / (w0 + w1 + 1e-6f);
    w0 *= inv; w1 *= inv;
    if (i0 < 8) { int pos = atomicAdd(&counts[i0], 1); lists[i0 * T_TOK + pos] = t;            wlist[i0 * T_TOK + pos] = w0; }
    if (i1 < 8) { int pos = atomicAdd(&counts[i1], 1); lists[i1 * T_TOK + pos] = t | (1 << 12); wlist[i1 * T_TOK + pos] = w1; }
  }
}

// ---------------- aux losses ----------------
__global__ void losses_kernel(const int* __restrict__ counts,
                              const float* __restrict__ z_sum,
                              float* __restrict__ outs) {
  if (threadIdx.x != 0 || blockIdx.x != 0) return;
  float loads[9]; float s = 0.f;
  for (int e = 0; e < 8; ++e) { loads[e] = (float)counts[e]; s += loads[e]; }
  loads[8] = (float)T_TOK; s += loads[8];
  float inv = 1.f / (s + 1e-6f);
  float ideal = 1.f / 9.f, lb = 0.f;
  for (int e = 0; e < 9; ++e) { float d = loads[e] * inv - ideal; lb += d * d; }
  lb /= 9.f;
  float zl = z_sum[0] / (float)T_TOK;
  outs[0] = 0.01f * lb + 0.01f * zl;
  outs[1] = lb;
  outs[2] = zl;
}

// ---------------- gate+up GEMM: hidden[srow, i] = silu(x.G^T) * (x.U^T) ----------------
// BM=128, BN=64 (per B matrix), BK=64, 4 waves (2x2), wave tile 64x32 per matrix
__global__ __launch_bounds__(256) void gateup_kernel(
    const u16* __restrict__ xb, const u16* __restrict__ gwb, const u16* __restrict__ upb,
    const int* __restrict__ lists, const int* __restrict__ counts, u16* __restrict__ hidden)
{
  int e = blockIdx.z;
  int count = (e == 8) ? T_TOK : counts[e];
  int m0 = blockIdx.y * 128;
  if (m0 >= count) return;
  int n0 = blockIdx.x * 64;
  const u16* gw = gwb + (size_t)e * I_DIM * H_DIM;
  const u16* uw = upb + (size_t)e * I_DIM * H_DIM;

  __shared__ __align__(16) u16 As[128 * 64];
  __shared__ __align__(16) u16 Bgs[64 * 64];
  __shared__ __align__(16) u16 Bus[64 * 64];
  __shared__ int tok_s[128];
  __shared__ int srow_s[128];

  int tid = threadIdx.x;
  if (tid < 128) {
    int rg = m0 + tid;
    int tok, srow;
    if (e == 8)            { tok = rg; srow = 2 * T_TOK + rg; }
    else if (rg < count)   { int p = lists[e * T_TOK + rg]; tok = p & 4095; srow = (p >> 12) * T_TOK + tok; }
    else                   { tok = 0; srow = 0; }
    tok_s[tid] = tok; srow_s[tid] = srow;
  }
  __syncthreads();

  // per-thread staging sources (inverse-swizzled global addresses, linear LDS dest)
  const u16* asrc[4];
#pragma unroll
  for (int c = 0; c < 4; ++c) {
    int row = c * 32 + (tid >> 3);
    int col = ((tid & 7) ^ (row & 7)) * 8;
    asrc[c] = xb + (size_t)tok_s[row] * H_DIM + col;
  }
  const u16 *gsrc[2], *usrc[2];
#pragma unroll
  for (int c = 0; c < 2; ++c) {
    int row = c * 32 + (tid >> 3);
    int col = ((tid & 7) ^ (row & 7)) * 8;
    gsrc[c] = gw + (size_t)(n0 + row) * H_DIM + col;
    usrc[c] = uw + (size_t)(n0 + row) * H_DIM + col;
  }

  int lane = tid & 63, wid = tid >> 6;
  int wm = wid >> 1, wn = wid & 1;

  f32x4 accg[4][2] = {};
  f32x4 accu[4][2] = {};

  for (int kt = 0; kt < H_DIM / 64; ++kt) {
    int k0 = kt * 64;
#pragma unroll
    for (int c = 0; c < 4; ++c) gload_lds16(asrc[c] + k0, (void*)(As + c * 2048 + tid * 8));
#pragma unroll
    for (int c = 0; c < 2; ++c) {
      gload_lds16(gsrc[c] + k0, (void*)(Bgs + c * 2048 + tid * 8));
      gload_lds16(usrc[c] + k0, (void*)(Bus + c * 2048 + tid * 8));
    }
    __syncthreads();
#pragma unroll
    for (int kk = 0; kk < 2; ++kk) {
      bf16x8 a[4], bg[2], bu[2];
      int kof = kk * 32 + (lane >> 4) * 8;
#pragma unroll
      for (int mI = 0; mI < 4; ++mI)
        a[mI] = lds_read_swz(As, wm * 64 + mI * 16 + (lane & 15), kof);
#pragma unroll
      for (int nI = 0; nI < 2; ++nI) {
        bg[nI] = lds_read_swz(Bgs, wn * 32 + nI * 16 + (lane & 15), kof);
        bu[nI] = lds_read_swz(Bus, wn * 32 + nI * 16 + (lane & 15), kof);
      }
#pragma unroll
      for (int mI = 0; mI < 4; ++mI)
#pragma unroll
        for (int nI = 0; nI < 2; ++nI) {
          accg[mI][nI] = __builtin_amdgcn_mfma_f32_16x16x32_bf16(a[mI], bg[nI], accg[mI][nI], 0, 0, 0);
          accu[mI][nI] = __builtin_amdgcn_mfma_f32_16x16x32_bf16(a[mI], bu[nI], accu[mI][nI], 0, 0, 0);
        }
    }
    __syncthreads();
  }

  // epilogue: silu(g)*u -> bf16 hidden (skip padded rows)
#pragma unroll
  for (int mI = 0; mI < 4; ++mI) {
#pragma unroll
    for (int j = 0; j < 4; ++j) {
      int rloc = wm * 64 + mI * 16 + (lane >> 4) * 4 + j;
      int rg = m0 + rloc;
      if (rg >= count) continue;
      int srow = srow_s[rloc];
#pragma unroll
      for (int nI = 0; nI < 2; ++nI) {
        int i = n0 + wn * 32 + nI * 16 + (lane & 15);
        float g = accg[mI][nI][j], u = accu[mI][nI][j];
        float h = (g / (1.f + __expf(-g))) * u;
        hidden[(size_t)srow * I_DIM + i] = f2bf(h);
      }
    }
  }
}

// ---------------- down GEMM + weighted scatter ----------------
// BM=64, BN=128, BK=64, 4 waves (2x2), wave tile 32x64
__global__ __launch_bounds__(256) void down_kernel(
    const u16* __restrict__ hidden, const u16* __restrict__ dwb,
    const int* __restrict__ lists, const float* __restrict__ wlist,
    const int* __restrict__ counts, float* __restrict__ out)
{
  int e = blockIdx.z;
  int count = (e == 8) ? T_TOK : counts[e];
  int m0 = blockIdx.y * 64;
  if (m0 >= count) return;
  int n0 = blockIdx.x * 128;
  const u16* dw = dwb + (size_t)e * H_DIM * I_DIM;

  __shared__ __align__(16) u16 As[64 * 64];
  __shared__ __align__(16) u16 Bs[128 * 64];
  __shared__ int tok_s[64];
  __shared__ int srow_s[64];
  __shared__ float w_s[64];

  int tid = threadIdx.x;
  if (tid < 64) {
    int rg = m0 + tid;
    int tok, srow; float w;
    if (e == 8)          { tok = rg; srow = 2 * T_TOK + rg; w = 1.f; }
    else if (rg < count) { int p = lists[e * T_TOK + rg]; tok = p & 4095; srow = (p >> 12) * T_TOK + tok; w = wlist[e * T_TOK + rg]; }
    else                 { tok = 0; srow = 0; w = 0.f; }
    tok_s[tid] = tok; srow_s[tid] = srow; w_s[tid] = w;
  }
  __syncthreads();

  const u16* asrc[2];
#pragma unroll
  for (int c = 0; c < 2; ++c) {
    int row = c * 32 + (tid >> 3);
    int col = ((tid & 7) ^ (row & 7)) * 8;
    asrc[c] = hidden + (size_t)srow_s[row] * I_DIM + col;
  }
  const u16* bsrc[4];
#pragma unroll
  for (int c = 0; c < 4; ++c) {
    int row = c * 32 + (tid >> 3);
    int col = ((tid & 7) ^ (row & 7)) * 8;
    bsrc[c] = dw + (size_t)(n0 + row) * I_DIM + col;
  }

  int lane = tid & 63, wid = tid >> 6;
  int wm = wid >> 1, wn = wid & 1;

  f32x4 acc[2][4] = {};

  for (int kt = 0; kt < I_DIM / 64; ++kt) {
    int k0 = kt * 64;
#pragma unroll
    for (int c = 0; c < 2; ++c) gload_lds16(asrc[c] + k0, (void*)(As + c * 2048 + tid * 8));
#pragma unroll
    for (int c = 0; c < 4; ++c) gload_lds16(bsrc[c] + k0, (void*)(Bs + c * 2048 + tid * 8));
    __syncthreads();
#pragma unroll
    for (int kk = 0; kk < 2; ++kk) {
      bf16x8 a[2], b[4];
      int kof = kk * 32 + (lane >> 4) * 8;
#pragma unroll
      for (int mI = 0; mI < 2; ++mI)
        a[mI] = lds_read_swz(As, wm * 32 + mI * 16 + (lane & 15), kof);
#pragma unroll
      for (int nI = 0; nI < 4; ++nI)
        b[nI] = lds_read_swz(Bs, wn * 64 + nI * 16 + (lane & 15), kof);
#pragma unroll
      for (int mI = 0; mI < 2; ++mI)
#pragma unroll
        for (int nI = 0; nI < 4; ++nI)
          acc[mI][nI] = __builtin_amdgcn_mfma_f32_16x16x32_bf16(a[mI], b[nI], acc[mI][nI], 0, 0, 0);
    }
    __syncthreads();
  }

#pragma unroll
  for (int mI = 0; mI < 2; ++mI) {
#pragma unroll
    for (int j = 0; j < 4; ++j) {
      int rloc = wm * 32 + mI * 16 + (lane >> 4) * 4 + j;
      int rg = m0 + rloc;
      if (rg >= count) continue;
      int tok = tok_s[rloc];
      float w = w_s[rloc];
#pragma unroll
      for (int nI = 0; nI < 4; ++nI) {
        int h = n0 + wn * 64 + nI * 16 + (lane & 15);
        atomicAdd(&out[(size_t)tok * H_DIM + h], w * acc[mI][nI][j]);
      }
    }
  }
}

extern "C" void kernel_launch(void* const* d_in, const int* in_sizes, int n_in,
                              void* d_out, int out_size, void* d_ws, size_t ws_size,
                              hipStream_t stream)
{
  const float* x   = (const float*)d_in[0];
  const float* rw  = (const float*)d_in[1];
  const float* gw  = (const float*)d_in[2];
  const float* uw  = (const float*)d_in[3];
  const float* dw  = (const float*)d_in[4];
  const float* sgw = (const float*)d_in[5];
  const float* suw = (const float*)d_in[6];
  const float* sdw = (const float*)d_in[7];
  float* out = (float*)d_out;

  char* ws = (char*)d_ws;
  size_t off = 0;
  auto alloc = [&](size_t bytes) { void* p = ws + off; off += (bytes + 255) & ~255ULL; return p; };
  u16* xb     = (u16*)alloc((size_t)T_TOK * H_DIM * 2);
  u16* gwb    = (u16*)alloc((size_t)9 * I_DIM * H_DIM * 2);
  u16* upb    = (u16*)alloc((size_t)9 * I_DIM * H_DIM * 2);
  u16* dwb    = (u16*)alloc((size_t)9 * H_DIM * I_DIM * 2);
  u16* hidden = (u16*)alloc((size_t)3 * T_TOK * I_DIM * 2);
  int*   lists  = (int*)alloc(8 * T_TOK * 4);
  float* wl     = (float*)alloc(8 * T_TOK * 4);
  int*   counts = (int*)alloc(256);
  float* z_sum  = (float*)alloc(256);

  hipMemsetAsync(d_out, 0, (size_t)out_size * 4, stream);
  hipMemsetAsync(counts, 0, 512, stream);  // counts + z_sum (contiguous allocs)

  const int EW = I_DIM * H_DIM;  // 4M elements per expert matrix
  cvt_kernel<<<2048, 256, 0, stream>>>(x,   xb, T_TOK * H_DIM);
  cvt_kernel<<<2048, 256, 0, stream>>>(gw,  gwb,            8 * EW);
  cvt_kernel<<<512,  256, 0, stream>>>(sgw, gwb + (size_t)8 * EW, EW);
  cvt_kernel<<<2048, 256, 0, stream>>>(uw,  upb,            8 * EW);
  cvt_kernel<<<512,  256, 0, stream>>>(suw, upb + (size_t)8 * EW, EW);
  cvt_kernel<<<2048, 256, 0, stream>>>(dw,  dwb,            8 * EW);
  cvt_kernel<<<512,  256, 0, stream>>>(sdw, dwb + (size_t)8 * EW, EW);

  router_kernel<<<T_TOK, 256, 0, stream>>>(x, rw, counts, lists, wl, z_sum);
  losses_kernel<<<1, 64, 0, stream>>>(counts, z_sum, out + (size_t)T_TOK * H_DIM);

  gateup_kernel<<<dim3(I_DIM / 64, T_TOK / 128, 9), 256, 0, stream>>>(xb, gwb, upb, lists, counts, hidden);
  down_kernel<<<dim3(H_DIM / 128, T_TOK / 64, 9), 256, 0, stream>>>(hidden, dwb, lists, wl, counts, out);
}

// Round 3
// 697.946 us; speedup vs baseline: 1.0902x; 1.0902x over previous
//
#include <hip/hip_runtime.h>
#include <hip/hip_bf16.h>
#include <stdint.h>

#define T_TOK 2048
#define H_DIM 1024
#define I_DIM 4096

typedef __attribute__((ext_vector_type(8))) short bf16x8;
typedef __attribute__((ext_vector_type(4))) float f32x4;
typedef unsigned short u16;

__device__ __forceinline__ void gload_lds16(const void* g, void* l) {
  __builtin_amdgcn_global_load_lds((const __attribute__((address_space(1))) void*)g,
                                   (__attribute__((address_space(3))) void*)l, 16, 0, 0);
}

__device__ __forceinline__ u16 f2bf(float f) {
  uint32_t u = __float_as_uint(f);
  u += 0x7fff + ((u >> 16) & 1);   // RNE
  return (u16)(u >> 16);
}

// swizzled LDS read: logical (row, kof elems) from a [*][64]-bf16 tile,
// phys byte = logical byte ^ ((row&7)<<4)
__device__ __forceinline__ bf16x8 lds_read_swz(const u16* base, int row, int kof) {
  int byt = (row * 64 + kof) * 2;
  byt ^= (row & 7) << 4;
  return *(const bf16x8*)((const char*)base + byt);
}

// pack 8 fp32 -> 8 bf16 (RNE via v_cvt_pk_bf16_f32) and store 16B to swizzled LDS
__device__ __forceinline__ void store16_swz(u16* base, int row, int colf,
                                            float4 a, float4 b) {
  union { __hip_bfloat162 h[4]; uint4 q; } o;
  o.h[0] = __float22bfloat162_rn({a.x, a.y});
  o.h[1] = __float22bfloat162_rn({a.z, a.w});
  o.h[2] = __float22bfloat162_rn({b.x, b.y});
  o.h[3] = __float22bfloat162_rn({b.z, b.w});
  int byt = ((row * 64 + colf) * 2) ^ ((row & 7) << 4);
  *(uint4*)((char*)base + byt) = o.q;
}

// ---------------- fp32 -> bf16 conversion (x only) ----------------
__global__ __launch_bounds__(256) void cvt_kernel(const float* __restrict__ s,
                                                  u16* __restrict__ d, int n) {
  int i = (blockIdx.x * 256 + threadIdx.x) * 8;
  int step = gridDim.x * 256 * 8;
  for (; i < n; i += step) {
    float4 v0 = *(const float4*)(s + i);
    float4 v1 = *(const float4*)(s + i + 4);
    union { u16 h[8]; uint4 q; } o;
    o.h[0] = f2bf(v0.x); o.h[1] = f2bf(v0.y); o.h[2] = f2bf(v0.z); o.h[3] = f2bf(v0.w);
    o.h[4] = f2bf(v1.x); o.h[5] = f2bf(v1.y); o.h[6] = f2bf(v1.z); o.h[7] = f2bf(v1.w);
    *(uint4*)(d + i) = o.q;
  }
}

// ---------------- router: fp32 logits, softmax, top-2 of 9 ----------------
__global__ __launch_bounds__(256) void router_kernel(
    const float* __restrict__ x, const float* __restrict__ rw,
    int* __restrict__ counts, int* __restrict__ lists, float* __restrict__ wlist,
    float* __restrict__ z_sum)
{
  int t = blockIdx.x;
  __shared__ float xs[H_DIM];
  __shared__ float red[9][4];
  const float* xp = x + (size_t)t * H_DIM;
  for (int h = threadIdx.x; h < H_DIM; h += 256) xs[h] = xp[h];
  __syncthreads();
  int lane = threadIdx.x & 63, wid = threadIdx.x >> 6;
  for (int e = 0; e < 9; ++e) {
    float p = 0.f;
    const float* rp = rw + e * H_DIM;
    for (int h = threadIdx.x; h < H_DIM; h += 256) p += xs[h] * rp[h];
#pragma unroll
    for (int off = 32; off > 0; off >>= 1) p += __shfl_down(p, off);
    if (lane == 0) red[e][wid] = p;
  }
  __syncthreads();
  if (threadIdx.x == 0) {
    float lg[9], m = -1e30f;
    for (int e = 0; e < 9; ++e) {
      lg[e] = red[e][0] + red[e][1] + red[e][2] + red[e][3];
      m = fmaxf(m, lg[e]);
    }
    float z = 0.f;
    for (int e = 0; e < 9; ++e) z += lg[e] * lg[e];
    atomicAdd(z_sum, z);
    float p[9], s = 0.f;
    for (int e = 0; e < 9; ++e) { p[e] = expf(lg[e] - m); s += p[e]; }
    int i0 = 0;
    for (int e = 1; e < 9; ++e) if (lg[e] > lg[i0]) i0 = e;
    int i1 = (i0 == 0) ? 1 : 0;
    for (int e = 0; e < 9; ++e) if (e != i0 && lg[e] > lg[i1]) i1 = e;
    float w0 = p[i0] / s, w1 = p[i1] / s;
    float inv = 1.f / (w0 + w1 + 1e-6f);
    w0 *= inv; w1 *= inv;
    if (i0 < 8) { int pos = atomicAdd(&counts[i0], 1); lists[i0 * T_TOK + pos] = t;            wlist[i0 * T_TOK + pos] = w0; }
    if (i1 < 8) { int pos = atomicAdd(&counts[i1], 1); lists[i1 * T_TOK + pos] = t | (1 << 12); wlist[i1 * T_TOK + pos] = w1; }
  }
}

// ---------------- aux losses ----------------
__global__ void losses_kernel(const int* __restrict__ counts,
                              const float* __restrict__ z_sum,
                              float* __restrict__ outs) {
  if (threadIdx.x != 0 || blockIdx.x != 0) return;
  float loads[9]; float s = 0.f;
  for (int e = 0; e < 8; ++e) { loads[e] = (float)counts[e]; s += loads[e]; }
  loads[8] = (float)T_TOK; s += loads[8];
  float inv = 1.f / (s + 1e-6f);
  float ideal = 1.f / 9.f, lb = 0.f;
  for (int e = 0; e < 9; ++e) { float d = loads[e] * inv - ideal; lb += d * d; }
  lb /= 9.f;
  float zl = z_sum[0] / (float)T_TOK;
  outs[0] = 0.01f * lb + 0.01f * zl;
  outs[1] = lb;
  outs[2] = zl;
}

// ---------------- gate+up GEMM: hidden[srow, i] = silu(x.G^T) * (x.U^T) ----------------
// BM=128 tokens, BN=64 (per matrix), BK=64. A (bf16) via global_load_lds;
// B (fp32 weights) reg-staged with fused cvt -> swizzled LDS.
__global__ __launch_bounds__(256) void gateup_kernel(
    const u16* __restrict__ xb,
    const float* __restrict__ gwf, const float* __restrict__ upf,
    const float* __restrict__ sgwf, const float* __restrict__ suwf,
    const int* __restrict__ lists, const int* __restrict__ counts,
    u16* __restrict__ hidden)
{
  int e = blockIdx.z;
  int count = (e == 8) ? T_TOK : counts[e];
  int m0 = blockIdx.y * 128;
  if (m0 >= count) return;
  int n0 = blockIdx.x * 64;
  const size_t EW = (size_t)I_DIM * H_DIM;
  const float* gw = (e == 8) ? sgwf : gwf + (size_t)e * EW;
  const float* uw = (e == 8) ? suwf : upf + (size_t)e * EW;

  __shared__ __align__(16) u16 As[128 * 64];
  __shared__ __align__(16) u16 Bgs[64 * 64];
  __shared__ __align__(16) u16 Bus[64 * 64];
  __shared__ int tok_s[128];
  __shared__ int srow_s[128];

  int tid = threadIdx.x;
  if (tid < 128) {
    int rg = m0 + tid;
    int tok, srow;
    if (e == 8)            { tok = rg; srow = 2 * T_TOK + rg; }
    else if (rg < count)   { int p = lists[e * T_TOK + rg]; tok = p & 4095; srow = (p >> 12) * T_TOK + tok; }
    else                   { tok = 0; srow = 0; }
    tok_s[tid] = tok; srow_s[tid] = srow;
  }
  __syncthreads();

  // A staging: inverse-swizzled global source, linear LDS dest (rule #21)
  const u16* asrc[4];
#pragma unroll
  for (int c = 0; c < 4; ++c) {
    int row = c * 32 + (tid >> 3);
    int col = ((tid & 7) ^ (row & 7)) * 8;
    asrc[c] = xb + (size_t)tok_s[row] * H_DIM + col;
  }
  // B staging: fp32 sources, linear order (cvt+swizzle happen at ds_write)
  int brow[2], bcolf;
  const float *gsrc[2], *usrc[2];
  bcolf = (tid & 7) * 8;
#pragma unroll
  for (int c = 0; c < 2; ++c) {
    brow[c] = c * 32 + (tid >> 3);
    gsrc[c] = gw + (size_t)(n0 + brow[c]) * H_DIM + bcolf;
    usrc[c] = uw + (size_t)(n0 + brow[c]) * H_DIM + bcolf;
  }

  int lane = tid & 63, wid = tid >> 6;
  int wm = wid >> 1, wn = wid & 1;

  f32x4 accg[4][2] = {};
  f32x4 accu[4][2] = {};

  for (int kt = 0; kt < H_DIM / 64; ++kt) {
    int k0 = kt * 64;
#pragma unroll
    for (int c = 0; c < 4; ++c) gload_lds16(asrc[c] + k0, (void*)(As + c * 2048 + tid * 8));
#pragma unroll
    for (int c = 0; c < 2; ++c) {
      float4 g0 = *(const float4*)(gsrc[c] + k0);
      float4 g1 = *(const float4*)(gsrc[c] + k0 + 4);
      float4 u0 = *(const float4*)(usrc[c] + k0);
      float4 u1 = *(const float4*)(usrc[c] + k0 + 4);
      store16_swz(Bgs, brow[c], bcolf, g0, g1);
      store16_swz(Bus, brow[c], bcolf, u0, u1);
    }
    __syncthreads();
#pragma unroll
    for (int kk = 0; kk < 2; ++kk) {
      bf16x8 a[4], bg[2], bu[2];
      int kof = kk * 32 + (lane >> 4) * 8;
#pragma unroll
      for (int mI = 0; mI < 4; ++mI)
        a[mI] = lds_read_swz(As, wm * 64 + mI * 16 + (lane & 15), kof);
#pragma unroll
      for (int nI = 0; nI < 2; ++nI) {
        bg[nI] = lds_read_swz(Bgs, wn * 32 + nI * 16 + (lane & 15), kof);
        bu[nI] = lds_read_swz(Bus, wn * 32 + nI * 16 + (lane & 15), kof);
      }
#pragma unroll
      for (int mI = 0; mI < 4; ++mI)
#pragma unroll
        for (int nI = 0; nI < 2; ++nI) {
          accg[mI][nI] = __builtin_amdgcn_mfma_f32_16x16x32_bf16(a[mI], bg[nI], accg[mI][nI], 0, 0, 0);
          accu[mI][nI] = __builtin_amdgcn_mfma_f32_16x16x32_bf16(a[mI], bu[nI], accu[mI][nI], 0, 0, 0);
        }
    }
    __syncthreads();
  }

#pragma unroll
  for (int mI = 0; mI < 4; ++mI) {
#pragma unroll
    for (int j = 0; j < 4; ++j) {
      int rloc = wm * 64 + mI * 16 + (lane >> 4) * 4 + j;
      int rg = m0 + rloc;
      if (rg >= count) continue;
      int srow = srow_s[rloc];
#pragma unroll
      for (int nI = 0; nI < 2; ++nI) {
        int i = n0 + wn * 32 + nI * 16 + (lane & 15);
        float g = accg[mI][nI][j], u = accu[mI][nI][j];
        float h = (g / (1.f + __expf(-g))) * u;
        hidden[(size_t)srow * I_DIM + i] = f2bf(h);
      }
    }
  }
}

// ---------------- down GEMM + weighted scatter ----------------
// BM=128 tokens, BN=64 (H cols), BK=64 over I. A (hidden bf16) via
// global_load_lds; B (down fp32) reg-staged with fused cvt.
__global__ __launch_bounds__(256) void down_kernel(
    const u16* __restrict__ hidden,
    const float* __restrict__ dwf, const float* __restrict__ sdwf,
    const int* __restrict__ lists, const float* __restrict__ wlist,
    const int* __restrict__ counts, float* __restrict__ out)
{
  int e = blockIdx.z;
  int count = (e == 8) ? T_TOK : counts[e];
  int m0 = blockIdx.y * 128;
  if (m0 >= count) return;
  int n0 = blockIdx.x * 64;
  const float* dw = (e == 8) ? sdwf : dwf + (size_t)e * H_DIM * I_DIM;

  __shared__ __align__(16) u16 As[128 * 64];
  __shared__ __align__(16) u16 Bs[64 * 64];
  __shared__ int tok_s[128];
  __shared__ int srow_s[128];
  __shared__ float w_s[128];

  int tid = threadIdx.x;
  if (tid < 128) {
    int rg = m0 + tid;
    int tok, srow; float w;
    if (e == 8)          { tok = rg; srow = 2 * T_TOK + rg; w = 1.f; }
    else if (rg < count) { int p = lists[e * T_TOK + rg]; tok = p & 4095; srow = (p >> 12) * T_TOK + tok; w = wlist[e * T_TOK + rg]; }
    else                 { tok = 0; srow = 0; w = 0.f; }
    tok_s[tid] = tok; srow_s[tid] = srow; w_s[tid] = w;
  }
  __syncthreads();

  const u16* asrc[4];
#pragma unroll
  for (int c = 0; c < 4; ++c) {
    int row = c * 32 + (tid >> 3);
    int col = ((tid & 7) ^ (row & 7)) * 8;
    asrc[c] = hidden + (size_t)srow_s[row] * I_DIM + col;
  }
  int brow[2], bcolf = (tid & 7) * 8;
  const float* bsrc[2];
#pragma unroll
  for (int c = 0; c < 2; ++c) {
    brow[c] = c * 32 + (tid >> 3);
    bsrc[c] = dw + (size_t)(n0 + brow[c]) * I_DIM + bcolf;
  }

  int lane = tid & 63, wid = tid >> 6;
  int wm = wid >> 1, wn = wid & 1;

  f32x4 acc[4][2] = {};

  for (int kt = 0; kt < I_DIM / 64; ++kt) {
    int k0 = kt * 64;
#pragma unroll
    for (int c = 0; c < 4; ++c) gload_lds16(asrc[c] + k0, (void*)(As + c * 2048 + tid * 8));
#pragma unroll
    for (int c = 0; c < 2; ++c) {
      float4 b0 = *(const float4*)(bsrc[c] + k0);
      float4 b1 = *(const float4*)(bsrc[c] + k0 + 4);
      store16_swz(Bs, brow[c], bcolf, b0, b1);
    }
    __syncthreads();
#pragma unroll
    for (int kk = 0; kk < 2; ++kk) {
      bf16x8 a[4], b[2];
      int kof = kk * 32 + (lane >> 4) * 8;
#pragma unroll
      for (int mI = 0; mI < 4; ++mI)
        a[mI] = lds_read_swz(As, wm * 64 + mI * 16 + (lane & 15), kof);
#pragma unroll
      for (int nI = 0; nI < 2; ++nI)
        b[nI] = lds_read_swz(Bs, wn * 32 + nI * 16 + (lane & 15), kof);
#pragma unroll
      for (int mI = 0; mI < 4; ++mI)
#pragma unroll
        for (int nI = 0; nI < 2; ++nI)
          acc[mI][nI] = __builtin_amdgcn_mfma_f32_16x16x32_bf16(a[mI], b[nI], acc[mI][nI], 0, 0, 0);
    }
    __syncthreads();
  }

#pragma unroll
  for (int mI = 0; mI < 4; ++mI) {
#pragma unroll
    for (int j = 0; j < 4; ++j) {
      int rloc = wm * 64 + mI * 16 + (lane >> 4) * 4 + j;
      int rg = m0 + rloc;
      if (rg >= count) continue;
      int tok = tok_s[rloc];
      float w = w_s[rloc];
#pragma unroll
      for (int nI = 0; nI < 2; ++nI) {
        int h = n0 + wn * 32 + nI * 16 + (lane & 15);
        atomicAdd(&out[(size_t)tok * H_DIM + h], w * acc[mI][nI][j]);
      }
    }
  }
}

extern "C" void kernel_launch(void* const* d_in, const int* in_sizes, int n_in,
                              void* d_out, int out_size, void* d_ws, size_t ws_size,
                              hipStream_t stream)
{
  const float* x   = (const float*)d_in[0];
  const float* rw  = (const float*)d_in[1];
  const float* gw  = (const float*)d_in[2];
  const float* uw  = (const float*)d_in[3];
  const float* dw  = (const float*)d_in[4];
  const float* sgw = (const float*)d_in[5];
  const float* suw = (const float*)d_in[6];
  const float* sdw = (const float*)d_in[7];
  float* out = (float*)d_out;

  char* ws = (char*)d_ws;
  size_t off = 0;
  auto alloc = [&](size_t bytes) { void* p = ws + off; off += (bytes + 255) & ~255ULL; return p; };
  u16* xb     = (u16*)alloc((size_t)T_TOK * H_DIM * 2);
  u16* hidden = (u16*)alloc((size_t)3 * T_TOK * I_DIM * 2);
  int*   lists  = (int*)alloc(8 * T_TOK * 4);
  float* wl     = (float*)alloc(8 * T_TOK * 4);
  int*   counts = (int*)alloc(256);
  float* z_sum  = (float*)alloc(256);

  hipMemsetAsync(d_out, 0, (size_t)out_size * 4, stream);
  hipMemsetAsync(counts, 0, 512, stream);  // counts + z_sum (contiguous allocs)

  cvt_kernel<<<1024, 256, 0, stream>>>(x, xb, T_TOK * H_DIM);
  router_kernel<<<T_TOK, 256, 0, stream>>>(x, rw, counts, lists, wl, z_sum);
  losses_kernel<<<1, 64, 0, stream>>>(counts, z_sum, out + (size_t)T_TOK * H_DIM);

  gateup_kernel<<<dim3(I_DIM / 64, T_TOK / 128, 9), 256, 0, stream>>>(
      xb, gw, uw, sgw, suw, lists, counts, hidden);
  down_kernel<<<dim3(H_DIM / 64, T_TOK / 128, 9), 256, 0, stream>>>(
      hidden, dw, sdw, lists, wl, counts, out);
}